// Round 6
// baseline (820.154 us; speedup 1.0000x reference)
//
#include <hip/hip_runtime.h>
#include <math.h>

// Problem constants (from reference)
constexpr int NN = 100000;          // nodes
constexpr int EE = 6400000;         // edges
constexpr int FF = 6;               // features
constexpr int RG = 500;             // reg head hidden
constexpr double MM = 600000.0;     // N*F elements for global norm

constexpr int NODE_BLOCK = 256;
constexpr int NODE_GRID  = (NN + NODE_BLOCK - 1) / NODE_BLOCK;   // 391

// bucket binning config
constexpr int BSH   = 6;                         // bucket shift
constexpr int BNODE = 1 << BSH;                  // 64 nodes per bucket
constexpr int NB    = (NN + BNODE - 1) / BNODE;  // 1563 buckets
constexpr int CHUNK = 8192;                      // edges per binning block
constexpr int NBLK  = (EE + CHUNK - 1) / CHUNK;  // 782 binning blocks

typedef unsigned uv2 __attribute__((ext_vector_type(2)));
typedef unsigned uv4 __attribute__((ext_vector_type(4)));
typedef float    fv2 __attribute__((ext_vector_type(2)));

__device__ __forceinline__ float leakyf(float v, float s) { return v >= 0.f ? v : s * v; }

__device__ __forceinline__ unsigned f2bf(float x) {   // RNE f32 -> bf16 bits
    unsigned u = __float_as_uint(x);
    return (u + 0x7FFFu + ((u >> 16) & 1u)) >> 16;
}

__device__ __forceinline__ void norm_params(const double* __restrict__ S, float& mu, float& istd) {
    double s1 = S[0], s2 = S[1];
    double mean = s1 / MM;
    double var  = (s2 - s1 * mean) / (MM - 1.0);
    mu   = (float)mean;
    istd = (float)(1.0 / sqrt(var));
}

// K0: collapse regression head; zero norm scalars.
__global__ void head_prep(const float* __restrict__ Wresh, const float* __restrict__ bresh,
                          const float* __restrict__ W1, const float* __restrict__ b1,
                          const float* __restrict__ W2, const float* __restrict__ b2,
                          float* __restrict__ head, double* __restrict__ S) {
    int t = threadIdx.x;
    if (t < 8) S[t] = 0.0;
    if (t < FF) {
        float a1 = 0.f, a2 = 0.f;
        for (int g = 0; g < RG; ++g) {
            float w = Wresh[t * RG + g];
            a1 = fmaf(w, W1[g], a1);
            a2 = fmaf(w, W2[g], a2);
        }
        head[t]     = a1;
        head[8 + t] = a2;
    } else if (t == FF) {
        float a1 = 0.f, a2 = 0.f;
        for (int g = 0; g < RG; ++g) {
            a1 = fmaf(bresh[g], W1[g], a1);
            a2 = fmaf(bresh[g], W2[g], a2);
        }
        head[6]  = a1 + b1[0];
        head[14] = a2 + b2[0];
    }
}

// reduce 2-double partials (no atomics anywhere)
__global__ __launch_bounds__(256)
void finish_norm(const double* __restrict__ part, int cnt, double* __restrict__ S) {
    __shared__ double sh[8];
    int wid = threadIdx.x >> 6, lane = threadIdx.x & 63;
    double s1 = 0.0, s2 = 0.0;
    for (int i = threadIdx.x; i < cnt; i += 256) {
        s1 += part[2 * i];
        s2 += part[2 * i + 1];
    }
    #pragma unroll
    for (int o = 32; o > 0; o >>= 1) {
        s1 += __shfl_down(s1, o, 64);
        s2 += __shfl_down(s2, o, 64);
    }
    if (lane == 0) { sh[wid * 2] = s1; sh[wid * 2 + 1] = s2; }
    __syncthreads();
    if (threadIdx.x == 0) {
        S[0] = sh[0] + sh[2] + sh[4] + sh[6];
        S[1] = sh[1] + sh[3] + sh[5] + sh[7];
    }
}

// ---------- bucket binning (no global atomics) ----------

// B1: per-(block,bucket) histogram via LDS atomics; coalesced row write.
__global__ __launch_bounds__(256)
void hist_bin(const int* __restrict__ ei, unsigned* __restrict__ blockCnt) {
    __shared__ unsigned hist[NB];
    for (int b = threadIdx.x; b < NB; b += 256) hist[b] = 0u;
    __syncthreads();
    int e0 = blockIdx.x * CHUNK;
    for (int i = threadIdx.x; i < CHUNK; i += 256) {
        int e = e0 + i;
        if (e < EE) {
            int d = __builtin_nontemporal_load(ei + EE + e) % NN;
            atomicAdd(&hist[d >> BSH], 1u);
        }
    }
    __syncthreads();
    for (int b = threadIdx.x; b < NB; b += 256)
        blockCnt[(size_t)blockIdx.x * NB + b] = hist[b];
}

// B2: per-bucket exclusive scan over blocks (one block per bucket).
__global__ __launch_bounds__(1024)
void scan_blocks(unsigned* __restrict__ blockCnt, unsigned* __restrict__ bucketTotal) {
    __shared__ unsigned ls[1024];
    int b = blockIdx.x, t = threadIdx.x;
    unsigned v = (t < NBLK) ? blockCnt[(size_t)t * NB + b] : 0u;
    ls[t] = v;
    __syncthreads();
    for (int o = 1; o < 1024; o <<= 1) {
        unsigned add = (t >= o) ? ls[t - o] : 0u;
        __syncthreads();
        ls[t] += add;
        __syncthreads();
    }
    if (t < NBLK) blockCnt[(size_t)t * NB + b] = ls[t] - v;  // exclusive within bucket
    if (t == 1023) bucketTotal[b] = ls[1023];
}

// B3: exclusive scan of bucket totals -> bucketStart[NB+1].
__global__ __launch_bounds__(1024)
void scan_totals(const unsigned* __restrict__ tot, int* __restrict__ start) {
    __shared__ unsigned ls[1024];
    const int CH = (NB + 1023) / 1024;   // 2
    int t = threadIdx.x;
    int beg = t * CH, fin = min(beg + CH, NB);
    unsigned p = 0;
    for (int i = beg; i < fin; ++i) p += tot[i];
    ls[t] = p;
    __syncthreads();
    for (int o = 1; o < 1024; o <<= 1) {
        unsigned add = (t >= o) ? ls[t - o] : 0u;
        __syncthreads();
        ls[t] += add;
        __syncthreads();
    }
    unsigned run = (t > 0) ? ls[t - 1] : 0u;
    for (int i = beg; i < fin; ++i) { start[i] = (int)run; run += tot[i]; }
    if (t == 1023) start[NB] = (int)ls[1023];
}

// B4: scatter records to bucket-CSR using LDS cursors (exact, race-free).
// rec: {src(17b) | dst_local(6b)<<17, ea 2xbf16}
__global__ __launch_bounds__(256)
void scatter_bin(const int* __restrict__ ei, const float* __restrict__ eattr,
                 const unsigned* __restrict__ blockCnt, const int* __restrict__ bucketStart,
                 uv2* __restrict__ recs) {
    __shared__ int cur[NB];
    int blk = blockIdx.x;
    for (int b = threadIdx.x; b < NB; b += 256)
        cur[b] = bucketStart[b] + (int)blockCnt[(size_t)blk * NB + b];
    __syncthreads();
    int e0 = blk * CHUNK;
    for (int i = threadIdx.x; i < CHUNK; i += 256) {
        int e = e0 + i;
        if (e < EE) {
            int s = __builtin_nontemporal_load(ei + e) % NN;
            int d = __builtin_nontemporal_load(ei + EE + e) % NN;
            fv2 ea = __builtin_nontemporal_load(reinterpret_cast<const fv2*>(eattr) + e);
            int b = d >> BSH;
            int pos = atomicAdd(&cur[b], 1);
            uv2 rec;
            rec.x = (unsigned)s | ((unsigned)(d & (BNODE - 1)) << 17);
            rec.y = f2bf(ea.x) | (f2bf(ea.y) << 16);
            recs[pos] = rec;    // plain store: keep line hot in local L2 for merging
        }
    }
}

// ---------- node transform: xl (bf16 packed, 16B/node) + xr (fp32, stride 8) ----------
template <int LAYER>
__global__ __launch_bounds__(NODE_BLOCK)
void node_transform(const float* __restrict__ xin, const double* __restrict__ Snorm,
                    const float* __restrict__ Wl, const float* __restrict__ bl,
                    const float* __restrict__ Wr, const float* __restrict__ br,
                    uv4* __restrict__ xlb, float* __restrict__ xr,
                    float* __restrict__ x2out) {
    int n = blockIdx.x * blockDim.x + threadIdx.x;
    if (n >= NN) return;
    float v[FF];
    if (LAYER == 0) {
        #pragma unroll
        for (int f = 0; f < FF; ++f) v[f] = xin[n * FF + f];
    } else {
        float mu, istd;
        norm_params(Snorm, mu, istd);
        #pragma unroll
        for (int f = 0; f < FF; ++f) {
            v[f] = (xin[n * FF + f] - mu) * istd;
            x2out[n * FF + f] = v[f];
        }
    }
    float ol[FF], orr[FF];
    #pragma unroll
    for (int j = 0; j < FF; ++j) { ol[j] = bl[j]; orr[j] = br[j]; }
    #pragma unroll
    for (int k = 0; k < FF; ++k) {
        float vk = v[k];
        #pragma unroll
        for (int j = 0; j < FF; ++j) {
            ol[j]  = fmaf(vk, Wl[k * FF + j], ol[j]);
            orr[j] = fmaf(vk, Wr[k * FF + j], orr[j]);
        }
    }
    uv4 q;
    q.x = f2bf(ol[0]) | (f2bf(ol[1]) << 16);
    q.y = f2bf(ol[2]) | (f2bf(ol[3]) << 16);
    q.z = f2bf(ol[4]) | (f2bf(ol[5]) << 16);
    q.w = 0u;
    xlb[n] = q;
    float4* xr4 = reinterpret_cast<float4*>(xr + n * 8);
    xr4[0] = make_float4(orr[0], orr[1], orr[2], orr[3]);
    xr4[1] = make_float4(orr[4], orr[5], 0.f, 0.f);
}

// compute one record's contribution and accumulate into LDS
__device__ __forceinline__ void edge_acc(uv2 rec, uv4 q, bool valid,
                                         float (&acc)[7][BNODE], const float (&xrl)[FF][BNODE],
                                         const float we0[FF], const float we1[FF],
                                         const float at[FF]) {
    int dl = (rec.x >> 17) & (BNODE - 1);
    float eax = __uint_as_float(rec.y << 16);
    float eay = __uint_as_float(rec.y & 0xFFFF0000u);
    float av[FF];
    av[0] = __uint_as_float(q.x << 16);
    av[1] = __uint_as_float(q.x & 0xFFFF0000u);
    av[2] = __uint_as_float(q.y << 16);
    av[3] = __uint_as_float(q.y & 0xFFFF0000u);
    av[4] = __uint_as_float(q.z << 16);
    av[5] = __uint_as_float(q.z & 0xFFFF0000u);
    float logit = 0.f;
    #pragma unroll
    for (int f = 0; f < FF; ++f) {
        float m = av[f] + xrl[f][dl] + fmaf(eay, we1[f], eax * we0[f]);
        m = m >= 0.f ? m : 0.2f * m;
        logit = fmaf(at[f], m, logit);
    }
    float w = __expf(logit);
    w = valid ? w : 0.f;
    atomicAdd(&acc[6][dl], w);               // native ds_add_f32
    #pragma unroll
    for (int f = 0; f < FF; ++f) atomicAdd(&acc[f][dl], w * av[f]);
}

// ---------- bucket gather: LDS-aggregated softmax + aggregate + finalize ----------
// one block per bucket of 64 nodes; 4 records per thread per iteration so the
// 4 independent xlb gathers (L1 misses) are in flight simultaneously (MLP=4).
template <int LAYER>
__global__ __launch_bounds__(256)
void bucket_gather(const int* __restrict__ bucketStart, const uv2* __restrict__ recs,
                   const uv4* __restrict__ xlb, const float* __restrict__ xr,
                   const float* __restrict__ Wef, const float* __restrict__ attf,
                   const float* __restrict__ biasg,
                   const float* __restrict__ x0, const float* __restrict__ x1n0,
                   const float* __restrict__ x2,
                   float* __restrict__ h, double* __restrict__ part) {
    __shared__ float acc[7][BNODE];     // [f=0..5]=num, [6]=denom
    __shared__ float xrl[FF][BNODE];
    __shared__ double shd[8];
    int b = blockIdx.x;
    int nb0 = b << BSH;
    int cnt = min(BNODE, NN - nb0);

    for (int i = threadIdx.x; i < 7 * BNODE; i += 256) acc[0][i] = 0.f;
    for (int i = threadIdx.x; i < BNODE * 8; i += 256) {
        int nl = i >> 3, f = i & 7;
        if (f < FF) xrl[f][nl] = (nl < cnt) ? xr[(size_t)(nb0 + nl) * 8 + f] : 0.f;
    }
    float we0[FF], we1[FF], at[FF];
    #pragma unroll
    for (int f = 0; f < FF; ++f) { we0[f] = Wef[f]; we1[f] = Wef[FF + f]; at[f] = attf[f]; }
    __syncthreads();

    int k0 = bucketStart[b], k1 = bucketStart[b + 1];
    int last = k1 - 1;
    for (int base = k0 + threadIdx.x * 4; base < k1; base += 1024) {
        // 4 independent rec loads (coalesced wave-wide: 64 lanes x 32B)
        uv2 rA = recs[base];
        uv2 rB = recs[min(base + 1, last)];
        uv2 rC = recs[min(base + 2, last)];
        uv2 rD = recs[min(base + 3, last)];
        // 4 independent random gathers -> 4 L1 misses in flight
        uv4 qA = xlb[rA.x & 0x1FFFF];
        uv4 qB = xlb[rB.x & 0x1FFFF];
        uv4 qC = xlb[rC.x & 0x1FFFF];
        uv4 qD = xlb[rD.x & 0x1FFFF];
        bool vB = base + 1 < k1, vC = base + 2 < k1, vD = base + 3 < k1;
        edge_acc(rA, qA, true, acc, xrl, we0, we1, at);
        edge_acc(rB, qB, vB,   acc, xrl, we0, we1, at);
        edge_acc(rC, qC, vC,   acc, xrl, we0, we1, at);
        edge_acc(rD, qD, vD,   acc, xrl, we0, we1, at);
    }
    __syncthreads();

    // finalize 64 nodes (threads 0..cnt-1); coalesced residual reads + h writes
    double s1 = 0.0, s2 = 0.0;
    if (threadIdx.x < cnt) {
        int nl = threadIdx.x;
        size_t n = nb0 + nl;
        float dn = acc[6][nl];
        float inv = dn != 0.f ? 1.f / dn : 0.f;
        #pragma unroll
        for (int f = 0; f < FF; ++f) {
            float t = leakyf(acc[f][nl] * inv + biasg[f], 0.01f);
            t += x0[n * FF + f];
            if (LAYER == 1) t += x1n0[n * FF + f] + x2[n * FF + f];
            h[n * FF + f] = t;
            s1 += t;
            s2 += (double)t * (double)t;
        }
    }
    int wid = threadIdx.x >> 6, lane = threadIdx.x & 63;
    #pragma unroll
    for (int o = 32; o > 0; o >>= 1) {
        s1 += __shfl_down(s1, o, 64);
        s2 += __shfl_down(s2, o, 64);
    }
    if (lane == 0) { shd[wid * 2] = s1; shd[wid * 2 + 1] = s2; }
    __syncthreads();
    if (threadIdx.x == 0) {
        part[b * 2 + 0] = shd[0] + shd[2] + shd[4] + shd[6];
        part[b * 2 + 1] = shd[1] + shd[3] + shd[5] + shd[7];
    }
}

// ---------- FFN ----------
template <int LAYER>
__global__ __launch_bounds__(NODE_BLOCK)
void node_ffn(const float* __restrict__ h, const double* __restrict__ Snorm,
              const float* __restrict__ f1W, const float* __restrict__ f1b,
              const float* __restrict__ f2W, const float* __restrict__ f2b,
              const float* __restrict__ x0, const float* __restrict__ x1n0_in,
              const float* __restrict__ x2,
              float* __restrict__ x1n0_out, float* __restrict__ gout,
              double* __restrict__ part,
              const float* __restrict__ head, float* __restrict__ dout) {
    __shared__ double sh[8];
    int n = blockIdx.x * blockDim.x + threadIdx.x;
    double s1 = 0.0, s2 = 0.0;
    if (n < NN) {
        float mu, istd;
        norm_params(Snorm, mu, istd);
        float xn[FF];
        #pragma unroll
        for (int f = 0; f < FF; ++f) xn[f] = (h[n * FF + f] - mu) * istd;

        float u[FF], w[FF];
        #pragma unroll
        for (int j = 0; j < FF; ++j) u[j] = f1b[j];
        #pragma unroll
        for (int k = 0; k < FF; ++k) {
            float vk = xn[k];
            #pragma unroll
            for (int j = 0; j < FF; ++j) u[j] = fmaf(vk, f1W[k * FF + j], u[j]);
        }
        #pragma unroll
        for (int j = 0; j < FF; ++j) u[j] = leakyf(u[j], 0.01f);
        #pragma unroll
        for (int j = 0; j < FF; ++j) w[j] = f2b[j];
        #pragma unroll
        for (int k = 0; k < FF; ++k) {
            float vk = u[k];
            #pragma unroll
            for (int j = 0; j < FF; ++j) w[j] = fmaf(vk, f2W[k * FF + j], w[j]);
        }
        #pragma unroll
        for (int f = 0; f < FF; ++f) {
            w[f] += xn[f] + x0[n * FF + f];
            if (LAYER == 1) w[f] += x2[n * FF + f] + x1n0_in[n * FF + f];
        }
        if (LAYER == 0) {
            #pragma unroll
            for (int f = 0; f < FF; ++f) {
                x1n0_out[n * FF + f] = xn[f];
                gout[n * FF + f]     = w[f];
                s1 += w[f];
                s2 += (double)w[f] * (double)w[f];
            }
        } else {
            float o1 = head[6], o2 = head[14];
            #pragma unroll
            for (int f = 0; f < FF; ++f) {
                o1 = fmaf(w[f], head[f], o1);
                o2 = fmaf(w[f], head[8 + f], o2);
            }
            dout[n * 2 + 0] = o1;
            dout[n * 2 + 1] = o2;
        }
    }
    if (LAYER == 0) {
        int wid = threadIdx.x >> 6, lane = threadIdx.x & 63;
        #pragma unroll
        for (int o = 32; o > 0; o >>= 1) {
            s1 += __shfl_down(s1, o, 64);
            s2 += __shfl_down(s2, o, 64);
        }
        if (lane == 0) { sh[wid * 2] = s1; sh[wid * 2 + 1] = s2; }
        __syncthreads();
        if (threadIdx.x == 0) {
            part[blockIdx.x * 2 + 0] = sh[0] + sh[2] + sh[4] + sh[6];
            part[blockIdx.x * 2 + 1] = sh[1] + sh[3] + sh[5] + sh[7];
        }
    }
}

// ---------------------------------------------------------------

extern "C" void kernel_launch(void* const* d_in, const int* in_sizes, int n_in,
                              void* d_out, int out_size, void* d_ws, size_t ws_size,
                              hipStream_t stream) {
    const float* x     = (const float*)d_in[0];
    const float* eattr = (const float*)d_in[1];
    const float* Wl    = (const float*)d_in[2];
    const float* bl    = (const float*)d_in[3];
    const float* Wr    = (const float*)d_in[4];
    const float* br    = (const float*)d_in[5];
    const float* We    = (const float*)d_in[6];
    const float* att   = (const float*)d_in[7];
    const float* biasg = (const float*)d_in[8];
    const float* ff1W  = (const float*)d_in[9];
    const float* ff1b  = (const float*)d_in[10];
    const float* ff2W  = (const float*)d_in[11];
    const float* ff2b  = (const float*)d_in[12];
    const float* Wresh = (const float*)d_in[13];
    const float* bresh = (const float*)d_in[14];
    const float* W1    = (const float*)d_in[15];
    const float* b1    = (const float*)d_in[16];
    const float* W2    = (const float*)d_in[17];
    const float* b2    = (const float*)d_in[18];
    const int*   ei    = (const int*)d_in[19];
    float* out = (float*)d_out;

    char* p = (char*)d_ws;
    auto alloc = [&](size_t bytes) -> char* {
        char* r = p;
        p += (bytes + 255) & ~size_t(255);
        return r;
    };

    double*   S        = (double*)alloc(8 * sizeof(double));
    float*    head     = (float*)alloc(16 * sizeof(float));
    double*   partA    = (double*)alloc((size_t)NB * 2 * sizeof(double));
    double*   partB    = (double*)alloc((size_t)NB * 2 * sizeof(double));
    double*   partF    = (double*)alloc((size_t)NODE_GRID * 2 * sizeof(double));
    uv4*      xlb      = (uv4*)alloc((size_t)NN * sizeof(uv4));           // 1.6 MB
    float*    xr       = (float*)alloc((size_t)NN * 8 * sizeof(float));   // 3.2 MB
    float*    h        = (float*)alloc((size_t)NN * FF * sizeof(float));
    float*    x1n0     = (float*)alloc((size_t)NN * FF * sizeof(float));
    float*    x2       = (float*)alloc((size_t)NN * FF * sizeof(float));
    float*    g        = (float*)alloc((size_t)NN * FF * sizeof(float));
    unsigned* blockCnt = (unsigned*)alloc((size_t)NBLK * NB * sizeof(unsigned)); // 4.9 MB
    unsigned* btot     = (unsigned*)alloc((size_t)NB * sizeof(unsigned));
    int*      bstart   = (int*)alloc((size_t)(NB + 1) * sizeof(int));
    uv2*      recs     = (uv2*)alloc((size_t)EE * sizeof(uv2));           // 51.2 MB

    head_prep<<<1, 64, 0, stream>>>(Wresh, bresh, W1, b1, W2, b2, head, S);

    // ---- bucket-CSR build (once; graph shared by both layers) ----
    hist_bin<<<NBLK, 256, 0, stream>>>(ei, blockCnt);
    scan_blocks<<<NB, 1024, 0, stream>>>(blockCnt, btot);
    scan_totals<<<1, 1024, 0, stream>>>(btot, bstart);
    scatter_bin<<<NBLK, 256, 0, stream>>>(ei, eattr, blockCnt, bstart, recs);

    // ---- layer 0 ----
    node_transform<0><<<NODE_GRID, NODE_BLOCK, 0, stream>>>(
        x, nullptr, Wl, bl, Wr, br, xlb, xr, nullptr);
    bucket_gather<0><<<NB, 256, 0, stream>>>(
        bstart, recs, xlb, xr, We, att, biasg, x, nullptr, nullptr, h, partA);
    finish_norm<<<1, 256, 0, stream>>>(partA, NB, S + 0);
    node_ffn<0><<<NODE_GRID, NODE_BLOCK, 0, stream>>>(
        h, S + 0, ff1W, ff1b, ff2W, ff2b, x, nullptr, nullptr,
        x1n0, g, partF, nullptr, nullptr);
    finish_norm<<<1, 256, 0, stream>>>(partF, NODE_GRID, S + 2);

    // ---- layer 1 ----
    node_transform<1><<<NODE_GRID, NODE_BLOCK, 0, stream>>>(
        g, S + 2, Wl + 36, bl + 6, Wr + 36, br + 6, xlb, xr, x2);
    bucket_gather<1><<<NB, 256, 0, stream>>>(
        bstart, recs, xlb, xr, We + 12, att + 6, biasg + 6, x, x1n0, x2, h, partB);
    finish_norm<<<1, 256, 0, stream>>>(partB, NB, S + 4);
    node_ffn<1><<<NODE_GRID, NODE_BLOCK, 0, stream>>>(
        h, S + 4, ff1W + 36, ff1b + 6, ff2W + 36, ff2b + 6, x, x1n0, x2,
        nullptr, nullptr, nullptr, head, out);
}

// Round 7
// 766.767 us; speedup vs baseline: 1.0696x; 1.0696x over previous
//
#include <hip/hip_runtime.h>
#include <math.h>

// Problem constants (from reference)
constexpr int NN = 100000;          // nodes
constexpr int EE = 6400000;         // edges
constexpr int FF = 6;               // features
constexpr int RG = 500;             // reg head hidden
constexpr double MM = 600000.0;     // N*F elements for global norm

constexpr int NODE_BLOCK = 256;
constexpr int NODE_GRID  = (NN + NODE_BLOCK - 1) / NODE_BLOCK;   // 391

// bucket binning config
constexpr int BSH   = 6;                         // bucket shift
constexpr int BNODE = 1 << BSH;                  // 64 nodes per bucket
constexpr int NB    = (NN + BNODE - 1) / BNODE;  // 1563 buckets
constexpr int CHUNK = 8192;                      // edges per binning block
constexpr int NBLK  = (EE + CHUNK - 1) / CHUNK;  // 782 binning blocks

constexpr int QSPLIT = 4;                        // blocks per bucket in gather
constexpr int ACCW   = 7 * BNODE;                // 448 floats per partial

typedef unsigned uv2 __attribute__((ext_vector_type(2)));
typedef unsigned uv4 __attribute__((ext_vector_type(4)));
typedef float    fv2 __attribute__((ext_vector_type(2)));

__device__ __forceinline__ float leakyf(float v, float s) { return v >= 0.f ? v : s * v; }

__device__ __forceinline__ unsigned f2bf(float x) {   // RNE f32 -> bf16 bits
    unsigned u = __float_as_uint(x);
    return (u + 0x7FFFu + ((u >> 16) & 1u)) >> 16;
}

__device__ __forceinline__ void norm_params(const double* __restrict__ S, float& mu, float& istd) {
    double s1 = S[0], s2 = S[1];
    double mean = s1 / MM;
    double var  = (s2 - s1 * mean) / (MM - 1.0);
    mu   = (float)mean;
    istd = (float)(1.0 / sqrt(var));
}

// K0: collapse regression head; zero norm scalars.
__global__ void head_prep(const float* __restrict__ Wresh, const float* __restrict__ bresh,
                          const float* __restrict__ W1, const float* __restrict__ b1,
                          const float* __restrict__ W2, const float* __restrict__ b2,
                          float* __restrict__ head, double* __restrict__ S) {
    int t = threadIdx.x;
    if (t < 8) S[t] = 0.0;
    if (t < FF) {
        float a1 = 0.f, a2 = 0.f;
        for (int g = 0; g < RG; ++g) {
            float w = Wresh[t * RG + g];
            a1 = fmaf(w, W1[g], a1);
            a2 = fmaf(w, W2[g], a2);
        }
        head[t]     = a1;
        head[8 + t] = a2;
    } else if (t == FF) {
        float a1 = 0.f, a2 = 0.f;
        for (int g = 0; g < RG; ++g) {
            a1 = fmaf(bresh[g], W1[g], a1);
            a2 = fmaf(bresh[g], W2[g], a2);
        }
        head[6]  = a1 + b1[0];
        head[14] = a2 + b2[0];
    }
}

// reduce 2-double partials (no atomics anywhere)
__global__ __launch_bounds__(256)
void finish_norm(const double* __restrict__ part, int cnt, double* __restrict__ S) {
    __shared__ double sh[8];
    int wid = threadIdx.x >> 6, lane = threadIdx.x & 63;
    double s1 = 0.0, s2 = 0.0;
    for (int i = threadIdx.x; i < cnt; i += 256) {
        s1 += part[2 * i];
        s2 += part[2 * i + 1];
    }
    #pragma unroll
    for (int o = 32; o > 0; o >>= 1) {
        s1 += __shfl_down(s1, o, 64);
        s2 += __shfl_down(s2, o, 64);
    }
    if (lane == 0) { sh[wid * 2] = s1; sh[wid * 2 + 1] = s2; }
    __syncthreads();
    if (threadIdx.x == 0) {
        S[0] = sh[0] + sh[2] + sh[4] + sh[6];
        S[1] = sh[1] + sh[3] + sh[5] + sh[7];
    }
}

// ---------- bucket binning (no global atomics) ----------

__global__ __launch_bounds__(256)
void hist_bin(const int* __restrict__ ei, unsigned* __restrict__ blockCnt) {
    __shared__ unsigned hist[NB];
    for (int b = threadIdx.x; b < NB; b += 256) hist[b] = 0u;
    __syncthreads();
    int e0 = blockIdx.x * CHUNK;
    for (int i = threadIdx.x; i < CHUNK; i += 256) {
        int e = e0 + i;
        if (e < EE) {
            int d = __builtin_nontemporal_load(ei + EE + e) % NN;
            atomicAdd(&hist[d >> BSH], 1u);
        }
    }
    __syncthreads();
    for (int b = threadIdx.x; b < NB; b += 256)
        blockCnt[(size_t)blockIdx.x * NB + b] = hist[b];
}

__global__ __launch_bounds__(1024)
void scan_blocks(unsigned* __restrict__ blockCnt, unsigned* __restrict__ bucketTotal) {
    __shared__ unsigned ls[1024];
    int b = blockIdx.x, t = threadIdx.x;
    unsigned v = (t < NBLK) ? blockCnt[(size_t)t * NB + b] : 0u;
    ls[t] = v;
    __syncthreads();
    for (int o = 1; o < 1024; o <<= 1) {
        unsigned add = (t >= o) ? ls[t - o] : 0u;
        __syncthreads();
        ls[t] += add;
        __syncthreads();
    }
    if (t < NBLK) blockCnt[(size_t)t * NB + b] = ls[t] - v;  // exclusive within bucket
    if (t == 1023) bucketTotal[b] = ls[1023];
}

__global__ __launch_bounds__(1024)
void scan_totals(const unsigned* __restrict__ tot, int* __restrict__ start) {
    __shared__ unsigned ls[1024];
    const int CH = (NB + 1023) / 1024;   // 2
    int t = threadIdx.x;
    int beg = t * CH, fin = min(beg + CH, NB);
    unsigned p = 0;
    for (int i = beg; i < fin; ++i) p += tot[i];
    ls[t] = p;
    __syncthreads();
    for (int o = 1; o < 1024; o <<= 1) {
        unsigned add = (t >= o) ? ls[t - o] : 0u;
        __syncthreads();
        ls[t] += add;
        __syncthreads();
    }
    unsigned run = (t > 0) ? ls[t - 1] : 0u;
    for (int i = beg; i < fin; ++i) { start[i] = (int)run; run += tot[i]; }
    if (t == 1023) start[NB] = (int)ls[1023];
}

// B4: scatter records to bucket-CSR using LDS cursors (exact, race-free).
// rec: {src(17b) | dst_local(6b)<<17, ea 2xbf16}
__global__ __launch_bounds__(256)
void scatter_bin(const int* __restrict__ ei, const float* __restrict__ eattr,
                 const unsigned* __restrict__ blockCnt, const int* __restrict__ bucketStart,
                 uv2* __restrict__ recs) {
    __shared__ int cur[NB];
    int blk = blockIdx.x;
    for (int b = threadIdx.x; b < NB; b += 256)
        cur[b] = bucketStart[b] + (int)blockCnt[(size_t)blk * NB + b];
    __syncthreads();
    int e0 = blk * CHUNK;
    for (int i = threadIdx.x; i < CHUNK; i += 256) {
        int e = e0 + i;
        if (e < EE) {
            int s = __builtin_nontemporal_load(ei + e) % NN;
            int d = __builtin_nontemporal_load(ei + EE + e) % NN;
            fv2 ea = __builtin_nontemporal_load(reinterpret_cast<const fv2*>(eattr) + e);
            int b = d >> BSH;
            int pos = atomicAdd(&cur[b], 1);
            uv2 rec;
            rec.x = (unsigned)s | ((unsigned)(d & (BNODE - 1)) << 17);
            rec.y = f2bf(ea.x) | (f2bf(ea.y) << 16);
            recs[pos] = rec;
        }
    }
}

// ---------- node transform: xl (bf16 packed, 16B/node) + xr (fp32, stride 8) ----------
template <int LAYER>
__global__ __launch_bounds__(NODE_BLOCK)
void node_transform(const float* __restrict__ xin, const double* __restrict__ Snorm,
                    const float* __restrict__ Wl, const float* __restrict__ bl,
                    const float* __restrict__ Wr, const float* __restrict__ br,
                    uv4* __restrict__ xlb, float* __restrict__ xr,
                    float* __restrict__ x2out) {
    int n = blockIdx.x * blockDim.x + threadIdx.x;
    if (n >= NN) return;
    float v[FF];
    if (LAYER == 0) {
        #pragma unroll
        for (int f = 0; f < FF; ++f) v[f] = xin[n * FF + f];
    } else {
        float mu, istd;
        norm_params(Snorm, mu, istd);
        #pragma unroll
        for (int f = 0; f < FF; ++f) {
            v[f] = (xin[n * FF + f] - mu) * istd;
            x2out[n * FF + f] = v[f];
        }
    }
    float ol[FF], orr[FF];
    #pragma unroll
    for (int j = 0; j < FF; ++j) { ol[j] = bl[j]; orr[j] = br[j]; }
    #pragma unroll
    for (int k = 0; k < FF; ++k) {
        float vk = v[k];
        #pragma unroll
        for (int j = 0; j < FF; ++j) {
            ol[j]  = fmaf(vk, Wl[k * FF + j], ol[j]);
            orr[j] = fmaf(vk, Wr[k * FF + j], orr[j]);
        }
    }
    uv4 q;
    q.x = f2bf(ol[0]) | (f2bf(ol[1]) << 16);
    q.y = f2bf(ol[2]) | (f2bf(ol[3]) << 16);
    q.z = f2bf(ol[4]) | (f2bf(ol[5]) << 16);
    q.w = 0u;
    xlb[n] = q;
    float4* xr4 = reinterpret_cast<float4*>(xr + n * 8);
    xr4[0] = make_float4(orr[0], orr[1], orr[2], orr[3]);
    xr4[1] = make_float4(orr[4], orr[5], 0.f, 0.f);
}

// compute one record's contribution and accumulate into LDS
__device__ __forceinline__ void edge_acc(uv2 rec, uv4 q, bool valid,
                                         float (&acc)[7][BNODE], const float (&xrl)[FF][BNODE],
                                         const float we0[FF], const float we1[FF],
                                         const float at[FF]) {
    int dl = (rec.x >> 17) & (BNODE - 1);
    float eax = __uint_as_float(rec.y << 16);
    float eay = __uint_as_float(rec.y & 0xFFFF0000u);
    float av[FF];
    av[0] = __uint_as_float(q.x << 16);
    av[1] = __uint_as_float(q.x & 0xFFFF0000u);
    av[2] = __uint_as_float(q.y << 16);
    av[3] = __uint_as_float(q.y & 0xFFFF0000u);
    av[4] = __uint_as_float(q.z << 16);
    av[5] = __uint_as_float(q.z & 0xFFFF0000u);
    float logit = 0.f;
    #pragma unroll
    for (int f = 0; f < FF; ++f) {
        float m = av[f] + xrl[f][dl] + fmaf(eay, we1[f], eax * we0[f]);
        m = m >= 0.f ? m : 0.2f * m;
        logit = fmaf(at[f], m, logit);
    }
    float w = __expf(logit);
    w = valid ? w : 0.f;
    atomicAdd(&acc[6][dl], w);               // native ds_add_f32
    #pragma unroll
    for (int f = 0; f < FF; ++f) atomicAdd(&acc[f][dl], w * av[f]);
}

// ---------- split bucket gather: QSPLIT blocks per bucket, private LDS acc ----------
// grid = NB*QSPLIT (6252 blocks -> ~8 resident blocks/CU, ~100% occupancy ceiling)
__global__ __launch_bounds__(256)
void bucket_gather_part(const int* __restrict__ bucketStart, const uv2* __restrict__ recs,
                        const uv4* __restrict__ xlb, const float* __restrict__ xr,
                        const float* __restrict__ Wef, const float* __restrict__ attf,
                        float* __restrict__ part_acc) {
    __shared__ float acc[7][BNODE];     // [f=0..5]=num, [6]=denom
    __shared__ float xrl[FF][BNODE];
    int b = blockIdx.x / QSPLIT;
    int qq = blockIdx.x % QSPLIT;
    int nb0 = b << BSH;
    int cnt = min(BNODE, NN - nb0);

    for (int i = threadIdx.x; i < 7 * BNODE; i += 256) acc[0][i] = 0.f;
    for (int i = threadIdx.x; i < BNODE * 8; i += 256) {
        int nl = i >> 3, f = i & 7;
        if (f < FF) xrl[f][nl] = (nl < cnt) ? xr[(size_t)(nb0 + nl) * 8 + f] : 0.f;
    }
    float we0[FF], we1[FF], at[FF];
    #pragma unroll
    for (int f = 0; f < FF; ++f) { we0[f] = Wef[f]; we1[f] = Wef[FF + f]; at[f] = attf[f]; }
    __syncthreads();

    int bk0 = bucketStart[b], bk1 = bucketStart[b + 1];
    int len = bk1 - bk0;
    int k0 = bk0 + (int)(((long long)len * qq) / QSPLIT);
    int k1 = bk0 + (int)(((long long)len * (qq + 1)) / QSPLIT);
    int last = k1 - 1;
    for (int base = k0 + threadIdx.x * 4; base < k1; base += 1024) {
        uv2 rA = recs[base];
        uv2 rB = recs[min(base + 1, last)];
        uv2 rC = recs[min(base + 2, last)];
        uv2 rD = recs[min(base + 3, last)];
        uv4 qA = xlb[rA.x & 0x1FFFF];
        uv4 qB = xlb[rB.x & 0x1FFFF];
        uv4 qC = xlb[rC.x & 0x1FFFF];
        uv4 qD = xlb[rD.x & 0x1FFFF];
        bool vB = base + 1 < k1, vC = base + 2 < k1, vD = base + 3 < k1;
        edge_acc(rA, qA, true, acc, xrl, we0, we1, at);
        edge_acc(rB, qB, vB,   acc, xrl, we0, we1, at);
        edge_acc(rC, qC, vC,   acc, xrl, we0, we1, at);
        edge_acc(rD, qD, vD,   acc, xrl, we0, we1, at);
    }
    __syncthreads();

    // coalesced partial write: 448 floats
    float* dst = part_acc + (size_t)blockIdx.x * ACCW;
    for (int i = threadIdx.x; i < ACCW; i += 256) dst[i] = acc[0][i];
}

// ---------- merge partials + finalize (one block of 64 threads per bucket) ----------
template <int LAYER>
__global__ __launch_bounds__(64)
void merge_finalize(const float* __restrict__ part_acc, const float* __restrict__ biasg,
                    const float* __restrict__ x0, const float* __restrict__ x1n0,
                    const float* __restrict__ x2,
                    float* __restrict__ h, double* __restrict__ part) {
    int b = blockIdx.x;
    int nb0 = b << BSH;
    int nl = threadIdx.x;
    int cnt = min(BNODE, NN - nb0);
    double s1 = 0.0, s2 = 0.0;
    if (nl < cnt) {
        size_t n = nb0 + nl;
        const float* pa = part_acc + (size_t)b * QSPLIT * ACCW;
        float a[7];
        #pragma unroll
        for (int f = 0; f < 7; ++f) {
            float v = 0.f;
            #pragma unroll
            for (int qq = 0; qq < QSPLIT; ++qq) v += pa[qq * ACCW + f * BNODE + nl];
            a[f] = v;
        }
        float inv = a[6] != 0.f ? 1.f / a[6] : 0.f;
        #pragma unroll
        for (int f = 0; f < FF; ++f) {
            float t = leakyf(a[f] * inv + biasg[f], 0.01f);
            t += x0[n * FF + f];
            if (LAYER == 1) t += x1n0[n * FF + f] + x2[n * FF + f];
            h[n * FF + f] = t;
            s1 += t;
            s2 += (double)t * (double)t;
        }
    }
    #pragma unroll
    for (int o = 32; o > 0; o >>= 1) {
        s1 += __shfl_down(s1, o, 64);
        s2 += __shfl_down(s2, o, 64);
    }
    if (nl == 0) {
        part[b * 2 + 0] = s1;
        part[b * 2 + 1] = s2;
    }
}

// ---------- FFN ----------
template <int LAYER>
__global__ __launch_bounds__(NODE_BLOCK)
void node_ffn(const float* __restrict__ h, const double* __restrict__ Snorm,
              const float* __restrict__ f1W, const float* __restrict__ f1b,
              const float* __restrict__ f2W, const float* __restrict__ f2b,
              const float* __restrict__ x0, const float* __restrict__ x1n0_in,
              const float* __restrict__ x2,
              float* __restrict__ x1n0_out, float* __restrict__ gout,
              double* __restrict__ part,
              const float* __restrict__ head, float* __restrict__ dout) {
    __shared__ double sh[8];
    int n = blockIdx.x * blockDim.x + threadIdx.x;
    double s1 = 0.0, s2 = 0.0;
    if (n < NN) {
        float mu, istd;
        norm_params(Snorm, mu, istd);
        float xn[FF];
        #pragma unroll
        for (int f = 0; f < FF; ++f) xn[f] = (h[n * FF + f] - mu) * istd;

        float u[FF], w[FF];
        #pragma unroll
        for (int j = 0; j < FF; ++j) u[j] = f1b[j];
        #pragma unroll
        for (int k = 0; k < FF; ++k) {
            float vk = xn[k];
            #pragma unroll
            for (int j = 0; j < FF; ++j) u[j] = fmaf(vk, f1W[k * FF + j], u[j]);
        }
        #pragma unroll
        for (int j = 0; j < FF; ++j) u[j] = leakyf(u[j], 0.01f);
        #pragma unroll
        for (int j = 0; j < FF; ++j) w[j] = f2b[j];
        #pragma unroll
        for (int k = 0; k < FF; ++k) {
            float vk = u[k];
            #pragma unroll
            for (int j = 0; j < FF; ++j) w[j] = fmaf(vk, f2W[k * FF + j], w[j]);
        }
        #pragma unroll
        for (int f = 0; f < FF; ++f) {
            w[f] += xn[f] + x0[n * FF + f];
            if (LAYER == 1) w[f] += x2[n * FF + f] + x1n0_in[n * FF + f];
        }
        if (LAYER == 0) {
            #pragma unroll
            for (int f = 0; f < FF; ++f) {
                x1n0_out[n * FF + f] = xn[f];
                gout[n * FF + f]     = w[f];
                s1 += w[f];
                s2 += (double)w[f] * (double)w[f];
            }
        } else {
            float o1 = head[6], o2 = head[14];
            #pragma unroll
            for (int f = 0; f < FF; ++f) {
                o1 = fmaf(w[f], head[f], o1);
                o2 = fmaf(w[f], head[8 + f], o2);
            }
            dout[n * 2 + 0] = o1;
            dout[n * 2 + 1] = o2;
        }
    }
    if (LAYER == 0) {
        int wid = threadIdx.x >> 6, lane = threadIdx.x & 63;
        #pragma unroll
        for (int o = 32; o > 0; o >>= 1) {
            s1 += __shfl_down(s1, o, 64);
            s2 += __shfl_down(s2, o, 64);
        }
        if (lane == 0) { sh[wid * 2] = s1; sh[wid * 2 + 1] = s2; }
        __syncthreads();
        if (threadIdx.x == 0) {
            part[blockIdx.x * 2 + 0] = sh[0] + sh[2] + sh[4] + sh[6];
            part[blockIdx.x * 2 + 1] = sh[1] + sh[3] + sh[5] + sh[7];
        }
    }
}

// ---------------------------------------------------------------

extern "C" void kernel_launch(void* const* d_in, const int* in_sizes, int n_in,
                              void* d_out, int out_size, void* d_ws, size_t ws_size,
                              hipStream_t stream) {
    const float* x     = (const float*)d_in[0];
    const float* eattr = (const float*)d_in[1];
    const float* Wl    = (const float*)d_in[2];
    const float* bl    = (const float*)d_in[3];
    const float* Wr    = (const float*)d_in[4];
    const float* br    = (const float*)d_in[5];
    const float* We    = (const float*)d_in[6];
    const float* att   = (const float*)d_in[7];
    const float* biasg = (const float*)d_in[8];
    const float* ff1W  = (const float*)d_in[9];
    const float* ff1b  = (const float*)d_in[10];
    const float* ff2W  = (const float*)d_in[11];
    const float* ff2b  = (const float*)d_in[12];
    const float* Wresh = (const float*)d_in[13];
    const float* bresh = (const float*)d_in[14];
    const float* W1    = (const float*)d_in[15];
    const float* b1    = (const float*)d_in[16];
    const float* W2    = (const float*)d_in[17];
    const float* b2    = (const float*)d_in[18];
    const int*   ei    = (const int*)d_in[19];
    float* out = (float*)d_out;

    char* p = (char*)d_ws;
    auto alloc = [&](size_t bytes) -> char* {
        char* r = p;
        p += (bytes + 255) & ~size_t(255);
        return r;
    };

    double*   S        = (double*)alloc(8 * sizeof(double));
    float*    head     = (float*)alloc(16 * sizeof(float));
    double*   partA    = (double*)alloc((size_t)NB * 2 * sizeof(double));
    double*   partB    = (double*)alloc((size_t)NB * 2 * sizeof(double));
    double*   partF    = (double*)alloc((size_t)NODE_GRID * 2 * sizeof(double));
    float*    partG    = (float*)alloc((size_t)NB * QSPLIT * ACCW * sizeof(float)); // 11.2 MB
    uv4*      xlb      = (uv4*)alloc((size_t)NN * sizeof(uv4));           // 1.6 MB
    float*    xr       = (float*)alloc((size_t)NN * 8 * sizeof(float));   // 3.2 MB
    float*    h        = (float*)alloc((size_t)NN * FF * sizeof(float));
    float*    x1n0     = (float*)alloc((size_t)NN * FF * sizeof(float));
    float*    x2       = (float*)alloc((size_t)NN * FF * sizeof(float));
    float*    g        = (float*)alloc((size_t)NN * FF * sizeof(float));
    unsigned* blockCnt = (unsigned*)alloc((size_t)NBLK * NB * sizeof(unsigned)); // 4.9 MB
    unsigned* btot     = (unsigned*)alloc((size_t)NB * sizeof(unsigned));
    int*      bstart   = (int*)alloc((size_t)(NB + 1) * sizeof(int));
    uv2*      recs     = (uv2*)alloc((size_t)EE * sizeof(uv2));           // 51.2 MB

    head_prep<<<1, 64, 0, stream>>>(Wresh, bresh, W1, b1, W2, b2, head, S);

    // ---- bucket-CSR build (once; graph shared by both layers) ----
    hist_bin<<<NBLK, 256, 0, stream>>>(ei, blockCnt);
    scan_blocks<<<NB, 1024, 0, stream>>>(blockCnt, btot);
    scan_totals<<<1, 1024, 0, stream>>>(btot, bstart);
    scatter_bin<<<NBLK, 256, 0, stream>>>(ei, eattr, blockCnt, bstart, recs);

    // ---- layer 0 ----
    node_transform<0><<<NODE_GRID, NODE_BLOCK, 0, stream>>>(
        x, nullptr, Wl, bl, Wr, br, xlb, xr, nullptr);
    bucket_gather_part<<<NB * QSPLIT, 256, 0, stream>>>(
        bstart, recs, xlb, xr, We, att, partG);
    merge_finalize<0><<<NB, 64, 0, stream>>>(
        partG, biasg, x, nullptr, nullptr, h, partA);
    finish_norm<<<1, 256, 0, stream>>>(partA, NB, S + 0);
    node_ffn<0><<<NODE_GRID, NODE_BLOCK, 0, stream>>>(
        h, S + 0, ff1W, ff1b, ff2W, ff2b, x, nullptr, nullptr,
        x1n0, g, partF, nullptr, nullptr);
    finish_norm<<<1, 256, 0, stream>>>(partF, NODE_GRID, S + 2);

    // ---- layer 1 ----
    node_transform<1><<<NODE_GRID, NODE_BLOCK, 0, stream>>>(
        g, S + 2, Wl + 36, bl + 6, Wr + 36, br + 6, xlb, xr, x2);
    bucket_gather_part<<<NB * QSPLIT, 256, 0, stream>>>(
        bstart, recs, xlb, xr, We + 12, att + 6, partG);
    merge_finalize<1><<<NB, 64, 0, stream>>>(
        partG, biasg + 6, x, x1n0, x2, h, partB);
    finish_norm<<<1, 256, 0, stream>>>(partB, NB, S + 4);
    node_ffn<1><<<NODE_GRID, NODE_BLOCK, 0, stream>>>(
        h, S + 4, ff1W + 36, ff1b + 6, ff2W + 36, ff2b + 6, x, x1n0, x2,
        nullptr, nullptr, nullptr, head, out);
}